// Round 1
// baseline (258.407 us; speedup 1.0000x reference)
//
#include <hip/hip_runtime.h>
#include <math.h>

// Problem constants
#define BB 32
#define NN 1024
#define DD 256
#define NCAP 32
#define DCAP 64

// ---------------------------------------------------------------------------
// colmean: t0p[b][p][k] = (1/1024) * sum_{jl=0..127} U[b, p*128+jl, k]
// grid (32, 8), block 256
__global__ __launch_bounds__(256) void k_colmean(const float* __restrict__ U,
                                                 float* __restrict__ t0p) {
    int b = blockIdx.x, p = blockIdx.y, k = threadIdx.x;
    const float* Up = U + (((b << 10) + (p << 7)) << 8) + k;
    float acc = 0.f;
    #pragma unroll 4
    for (int jl = 0; jl < 128; ++jl) acc += Up[jl << 8];
    t0p[(b << 11) + (p << 8) + k] = acc * (1.0f / 1024.0f);
}

// ---------------------------------------------------------------------------
// sv: per (b,i): t = sum of 8 partials; s[d] = sum_k t[k] W[k, i*64+d];
// v = s / sqrt(||s||^2 + eps); w[k] = sum_d W[k, i*64+d] v[d]
// writes v -> vout[(b*32+i)*64 + d], w -> wbt[b][k][i]  (transposed!)
// grid 1024 (= b*32+i), block 256
__global__ __launch_bounds__(256) void k_sv(const float* __restrict__ tbase, int mode,
                                            const float* __restrict__ W,
                                            float* __restrict__ vout,
                                            float* __restrict__ wbt) {
    __shared__ float t_lds[256];
    __shared__ float spart[256];
    __shared__ __align__(16) float v_lds[64];
    int bid = blockIdx.x, tid = threadIdx.x;
    int b = bid >> 5, i = bid & 31;

    // sum 8 partial t-buffers
    const float* tb;
    int pstr;
    if (mode == 0) { tb = tbase + (b << 11) + tid; pstr = 256; }       // t0p[b][p][k]
    else           { tb = tbase + (bid << 8) + tid; pstr = 262144; }   // tp[p][b][i][k]
    float acc = 0.f;
    #pragma unroll
    for (int p = 0; p < 8; ++p) acc += tb[p * pstr];
    t_lds[tid] = acc;
    __syncthreads();

    // s phase: thread = (d = tid&63, kq = tid>>6)
    int d = tid & 63, kq = tid >> 6;
    const float* Wc = W + ((kq << 6) * 2048) + i * 64 + d;
    float s = 0.f;
    #pragma unroll 4
    for (int kk = 0; kk < 64; ++kk)
        s += t_lds[(kq << 6) + kk] * Wc[kk * 2048];
    spart[tid] = s;
    __syncthreads();

    if (tid < 64) {
        float sv = spart[tid] + spart[tid + 64] + spart[tid + 128] + spart[tid + 192];
        float n2 = sv * sv;
        #pragma unroll
        for (int off = 1; off < 64; off <<= 1) n2 += __shfl_xor(n2, off, 64);
        float v = sv / sqrtf(n2 + 1e-7f);
        vout[(bid << 6) + tid] = v;
        v_lds[tid] = v;
    }
    __syncthreads();

    // w phase: thread = k
    const float4* Wr = (const float4*)(W + tid * 2048 + i * 64);
    const float4* v4 = (const float4*)v_lds;
    float w = 0.f;
    #pragma unroll
    for (int q = 0; q < 16; ++q) {
        float4 a = Wr[q], vv = v4[q];
        w += a.x * vv.x + a.y * vv.y + a.z * vv.z + a.w * vv.w;
    }
    wbt[(b << 13) + (tid << 5) + i] = w;   // [b][k][i]
}

// ---------------------------------------------------------------------------
// bupd: b[b, i, jbase+j] (+)= sum_k w[i][k] * U[b, jbase+j, k]   for all 32 i
// grid (32, 32) (b, j-chunk of 32), block 256 = (j = tid&31, kq = tid>>5)
__global__ __launch_bounds__(256) void k_bupd(const float* __restrict__ U,
                                              const float* __restrict__ wbt,
                                              float* __restrict__ bmat, int addold) {
    __shared__ __align__(16) float smem[12288];    // 48 KB
    float4* wl4 = (float4*)smem;                   // w_lds [k=256][i=32] -> idx k*8+ii
    float4* Ul4 = (float4*)(smem + 8192);          // U stage: [j=32][32 f4] swizzled
    int b = blockIdx.x, jc = blockIdx.y, tid = threadIdx.x;
    int jbase = jc << 5;
    int j = tid & 31, kq = tid >> 5;

    // load w (contiguous copy, already transposed [k][i] in global)
    const float4* wsrc = (const float4*)(wbt + (b << 13));
    for (int idx = tid; idx < 2048; idx += 256) wl4[idx] = wsrc[idx];

    float acc[32];
    #pragma unroll
    for (int i = 0; i < 32; ++i) acc[i] = 0.f;

    const float4* U4 = (const float4*)U;
    for (int s = 0; s < 2; ++s) {
        __syncthreads();
        // stage 128 k's (32 float4) for 32 j rows, swizzled to kill bank conflicts
        for (int idx = tid; idx < 1024; idx += 256) {
            int jl = idx >> 5, k4 = idx & 31;
            Ul4[(jl << 5) + ((k4 + jl) & 31)] =
                U4[(((b << 10) + jbase + jl) << 6) + (s << 5) + k4];
        }
        __syncthreads();
        #pragma unroll
        for (int m = 0; m < 4; ++m) {
            int k4 = (kq << 2) + m;
            float4 u4 = Ul4[(j << 5) + ((k4 + j) & 31)];
            int kg = (s << 7) + (k4 << 2);
            float uu[4] = {u4.x, u4.y, u4.z, u4.w};
            #pragma unroll
            for (int r = 0; r < 4; ++r) {
                float u = uu[r];
                #pragma unroll
                for (int ii = 0; ii < 8; ++ii) {
                    float4 w4 = wl4[((kg + r) << 3) + ii];  // broadcast
                    acc[ii * 4 + 0] += w4.x * u;
                    acc[ii * 4 + 1] += w4.y * u;
                    acc[ii * 4 + 2] += w4.z * u;
                    acc[ii * 4 + 3] += w4.w * u;
                }
            }
        }
    }
    __syncthreads();
    // cross-kq reduction through smem (reuse region): red[q][j][i], row pad 33
    float* red = smem;
    #pragma unroll
    for (int i = 0; i < 32; ++i) red[kq * 1056 + j * 33 + i] = acc[i];
    __syncthreads();
    if (tid < 32) {
        int jj = tid;
        for (int i = 0; i < 32; ++i) {
            float ssum = 0.f;
            #pragma unroll
            for (int q = 0; q < 8; ++q) ssum += red[q * 1056 + jj * 33 + i];
            int off = (((b << 5) + i) << 10) + jbase + jj;
            if (addold) ssum += bmat[off];
            bmat[off] = ssum;
        }
    }
}

// ---------------------------------------------------------------------------
// sumexp: se[b*32+i] = 1 / sum_j exp(b[b,i,j])   (no max-sub; |b| <= ~18)
// grid 1024, block 256
__global__ __launch_bounds__(256) void k_sumexp(const float* __restrict__ bmat,
                                                float* __restrict__ se) {
    __shared__ float wpart[4];
    int bid = blockIdx.x, tid = threadIdx.x;
    const float* br = bmat + (bid << 10);
    float s = 0.f;
    #pragma unroll
    for (int p = 0; p < 4; ++p) s += __expf(br[(p << 8) + tid]);
    #pragma unroll
    for (int off = 1; off < 64; off <<= 1) s += __shfl_xor(s, off, 64);
    if ((tid & 63) == 0) wpart[tid >> 6] = s;
    __syncthreads();
    if (tid == 0) se[bid] = 1.0f / (wpart[0] + wpart[1] + wpart[2] + wpart[3]);
}

// ---------------------------------------------------------------------------
// ctu: tp[p][b][i][k] = sum_{jl in chunk p} c[b,i,j] * U[b,j,k],
//      c = exp(bmat)*se.  grid 256 (= b*8+p), block 256 (thread = k)
__global__ __launch_bounds__(256) void k_ctu(const float* __restrict__ U,
                                             const float* __restrict__ bmat,
                                             const float* __restrict__ se,
                                             float* __restrict__ tp) {
    __shared__ __align__(16) float c_lds[128 * 36];   // [jl][36] (pad), float4 rows of 9
    int bx = blockIdx.x, tid = threadIdx.x;
    int b = bx >> 3, p = bx & 7, jbase = p << 7;

    for (int idx = tid; idx < 4096; idx += 256) {
        int i = idx >> 7, jl = idx & 127;
        float e = __expf(bmat[(((b << 5) + i) << 10) + jbase + jl]) * se[(b << 5) + i];
        c_lds[jl * 36 + i] = e;
    }
    __syncthreads();

    float t[32];
    #pragma unroll
    for (int i = 0; i < 32; ++i) t[i] = 0.f;

    const float* Up = U + (((b << 10) + jbase) << 8) + tid;
    const float4* c4 = (const float4*)c_lds;
    #pragma unroll 2
    for (int jl = 0; jl < 128; ++jl) {
        float u = Up[jl << 8];
        #pragma unroll
        for (int ii = 0; ii < 8; ++ii) {
            float4 c = c4[jl * 9 + ii];   // wave-uniform address: LDS broadcast
            t[ii * 4 + 0] += c.x * u;
            t[ii * 4 + 1] += c.y * u;
            t[ii * 4 + 2] += c.z * u;
            t[ii * 4 + 3] += c.w * u;
        }
    }
    #pragma unroll
    for (int i = 0; i < 32; ++i)
        tp[(p << 18) + (((b << 5) + i) << 8) + tid] = t[i];
}

// ---------------------------------------------------------------------------
extern "C" void kernel_launch(void* const* d_in, const int* in_sizes, int n_in,
                              void* d_out, int out_size, void* d_ws, size_t ws_size,
                              hipStream_t stream) {
    const float* U = (const float*)d_in[0];   // [32,1024,256]
    const float* W = (const float*)d_in[1];   // [256,2048]
    float* out = (float*)d_out;               // [32,32,64]
    float* ws = (float*)d_ws;

    // ws layout (floats); total 3,539,968 floats = 14.16 MB
    float* tp   = ws;                 // [8][32][32][256] = 2,097,152
    float* t0p  = tp + 2097152;       // [32][8][256]     =    65,536
    float* bmat = t0p + 65536;        // [32][32][1024]   = 1,048,576
    float* wbt  = bmat + 1048576;     // [32][256][32]    =   262,144
    float* se   = wbt + 262144;       // [32*32]          =     1,024
    float* vscr = se + 1024;          // [32][32][64]     =    65,536

    // iter 0: uniform c -> column mean
    k_colmean<<<dim3(32, 8), 256, 0, stream>>>(U, t0p);
    k_sv<<<1024, 256, 0, stream>>>(t0p, 0, W, vscr, wbt);
    k_bupd<<<dim3(32, 32), 256, 0, stream>>>(U, wbt, bmat, 0);
    // iter 1
    k_sumexp<<<1024, 256, 0, stream>>>(bmat, se);
    k_ctu<<<256, 256, 0, stream>>>(U, bmat, se, tp);
    k_sv<<<1024, 256, 0, stream>>>(tp, 1, W, vscr, wbt);
    k_bupd<<<dim3(32, 32), 256, 0, stream>>>(U, wbt, bmat, 1);
    // iter 2 (final: v -> d_out)
    k_sumexp<<<1024, 256, 0, stream>>>(bmat, se);
    k_ctu<<<256, 256, 0, stream>>>(U, bmat, se, tp);
    k_sv<<<1024, 256, 0, stream>>>(tp, 1, W, out, wbt);
}

// Round 2
// 212.762 us; speedup vs baseline: 1.2145x; 1.2145x over previous
//
#include <hip/hip_runtime.h>
#include <math.h>

// Problem: capsule routing, B=32, N=1024, D=256, NC=32, DC=64.
// Factored algebra: never materialize u_hat.
//   t[b,i,k]  = sum_j c[b,i,j] U[b,j,k]        (k_ctu / k_colmean for iter 0)
//   s[b,i,d]  = sum_k t[b,i,k] W[k, i*64+d]    (k_sv)
//   v         = s / sqrt(||s||^2 + eps)        (k_sv)
//   w[b,i,k]  = sum_d W[k, i*64+d] v[b,i,d]    (k_sv)
//   b[b,i,j] += sum_k U[b,j,k] w[b,i,k]        (k_bupd; stores emat=exp(b) and
//                                               accumulates softmax denom into sef)

// ---------------------------------------------------------------------------
// colmean: t0p[b][p][k] = (1/1024) * sum over 64-j chunk of U[b, j, k]
// grid (32, 16), block 256. Deep unroll => 16 loads in flight.
__global__ __launch_bounds__(256) void k_colmean(const float* __restrict__ U,
                                                 float* __restrict__ t0p) {
    int b = blockIdx.x, p = blockIdx.y, k = threadIdx.x;
    const float* Up = U + (((b << 10) + (p << 6)) << 8) + k;
    float acc = 0.f;
    #pragma unroll 16
    for (int jl = 0; jl < 64; ++jl) acc += Up[jl << 8];
    t0p[(b << 12) + (p << 8) + k] = acc * (1.0f / 1024.0f);
}

// ---------------------------------------------------------------------------
// sv: per (b,i): t = sum of partials; s[d] = sum_k t[k] W[k,i*64+d];
// v = s/sqrt(||s||^2+eps); w[k] = sum_d W[k,i*64+d] v[d]
// grid 1024 (= b*32+i), block 256
__global__ __launch_bounds__(256) void k_sv(const float* __restrict__ tbase, int mode,
                                            const float* __restrict__ W,
                                            float* __restrict__ vout,
                                            float* __restrict__ wbt) {
    __shared__ float t_lds[256];
    __shared__ float spart[256];
    __shared__ __align__(16) float v_lds[64];
    int bid = blockIdx.x, tid = threadIdx.x;
    int b = bid >> 5, i = bid & 31;

    const float* tb;
    int pstr, pc;
    if (mode == 0) { tb = tbase + (b << 12) + tid; pstr = 256;    pc = 16; }  // t0p[b][p][k]
    else           { tb = tbase + (bid << 8) + tid; pstr = 262144; pc = 8;  } // tp[p][b][i][k]
    float acc = 0.f;
    for (int p = 0; p < pc; ++p) acc += tb[p * pstr];
    t_lds[tid] = acc;
    __syncthreads();

    // s phase: thread = (d = tid&63, kq = tid>>6); W columns, 256B/wave coalesced
    int d = tid & 63, kq = tid >> 6;
    const float* Wc = W + ((kq << 6) * 2048) + i * 64 + d;
    float s = 0.f;
    #pragma unroll 4
    for (int kk = 0; kk < 64; ++kk)
        s += t_lds[(kq << 6) + kk] * Wc[kk * 2048];
    spart[tid] = s;
    __syncthreads();

    if (tid < 64) {
        float sv = spart[tid] + spart[tid + 64] + spart[tid + 128] + spart[tid + 192];
        float n2 = sv * sv;
        #pragma unroll
        for (int off = 1; off < 64; off <<= 1) n2 += __shfl_xor(n2, off, 64);
        float v = sv / sqrtf(n2 + 1e-7f);
        vout[(bid << 6) + tid] = v;
        v_lds[tid] = v;
    }
    __syncthreads();

    // w phase: thread = k
    const float4* Wr = (const float4*)(W + tid * 2048 + i * 64);
    const float4* v4 = (const float4*)v_lds;
    float w = 0.f;
    #pragma unroll
    for (int q = 0; q < 16; ++q) {
        float4 a = Wr[q], vv = v4[q];
        w += a.x * vv.x + a.y * vv.y + a.z * vv.z + a.w * vv.w;
    }
    wbt[(b << 13) + (tid << 5) + i] = w;   // [b][k][i]
}

// ---------------------------------------------------------------------------
// bupd v2: thread = (j = tid&31, ig = tid>>5); computes delta_b for (j, 4 i's)
// with the FULL k=256 reduction in-thread (acc[4], no LDS reduction tail).
// Epilogue: emat = (old? emat:1)*exp(delta); wave-reduce exp-sums over j,
// atomicAdd into sef[b*32+i]  (softmax denominator, replaces k_sumexp).
// grid (32 b, 32 jc), block 256. LDS 48 KB -> 3 blocks/CU.
__global__ __launch_bounds__(256, 3) void k_bupd(const float* __restrict__ U,
                                                 const float* __restrict__ wbt,
                                                 float* __restrict__ emat,
                                                 float* __restrict__ sef,
                                                 int addold) {
    __shared__ __align__(16) float smem[12288];    // 48 KB: wl 32 KB + Ust 16 KB
    float4* wl4 = (float4*)smem;                   // [k=256][i-quad=8] float4
    float4* Ul4 = (float4*)(smem + 8192);          // [j=32][32 f4] swizzled
    int b = blockIdx.x, jc = blockIdx.y, tid = threadIdx.x;
    int j = tid & 31, ig = tid >> 5;               // ig = i-quad index (0..7)

    // stage w [b][k][i] -> LDS (contiguous f4 copy)
    const float4* wsrc = (const float4*)(wbt + (b << 13));
    for (int idx = tid; idx < 2048; idx += 256) wl4[idx] = wsrc[idx];

    float acc0 = 0.f, acc1 = 0.f, acc2 = 0.f, acc3 = 0.f;
    const float4* U4 = (const float4*)U;

    for (int s = 0; s < 2; ++s) {
        __syncthreads();
        // stage 32 rows x 128 k (32 f4), swizzled to kill the stride-512B conflict
        for (int idx = tid; idx < 1024; idx += 256) {
            int jl = idx >> 5, k4 = idx & 31;
            Ul4[(jl << 5) + ((k4 + jl) & 31)] =
                U4[(((b << 10) + (jc << 5) + jl) << 6) + (s << 5) + k4];
        }
        __syncthreads();
        #pragma unroll
        for (int k4 = 0; k4 < 32; ++k4) {
            float4 u4 = Ul4[(j << 5) + ((k4 + j) & 31)];
            float uu[4] = {u4.x, u4.y, u4.z, u4.w};
            #pragma unroll
            for (int r = 0; r < 4; ++r) {
                float4 w4 = wl4[(((s << 7) + (k4 << 2) + r) << 3) + ig];
                acc0 += w4.x * uu[r];
                acc1 += w4.y * uu[r];
                acc2 += w4.z * uu[r];
                acc3 += w4.w * uu[r];
            }
        }
    }

    // epilogue: emat update + softmax-denominator partials
    int jg = (jc << 5) + j;
    float dl[4] = {acc0, acc1, acc2, acc3};
    #pragma unroll
    for (int q = 0; q < 4; ++q) {
        int i = (ig << 2) + q;
        long off = (long)(((b << 5) + i) << 10) + jg;
        float e = __expf(dl[q]);
        if (addold) e *= emat[off];
        emat[off] = e;
        // reduce e over the 32 j-lanes (bits 0..4; bit 5 separates the 2 ig's)
        float se = e;
        #pragma unroll
        for (int m = 1; m < 32; m <<= 1) se += __shfl_xor(se, m, 64);
        if (j == 0) atomicAdd(&sef[(b << 5) + i], se);
    }
}

// ---------------------------------------------------------------------------
// ctu v2: tp[p][b][i][k] = sum_{jl in 128-chunk} c[b,i,j] U[b,j,k],
// c = emat * (1/sef).  grid (32 b, 8 p), block 1024 (16 waves/CU).
// thread: k = tid&255, jq = tid>>8 covers 32 j's. All 32 u-values preloaded
// into registers (full MLP), then fully-unrolled FMA sweep vs LDS-broadcast c.
__global__ __launch_bounds__(1024, 4) void k_ctu(const float* __restrict__ U,
                                                 const float* __restrict__ emat,
                                                 const float* __restrict__ sef,
                                                 float* __restrict__ tp) {
    __shared__ __align__(16) float c_lds[128 * 36];  // [jl][i], row pad to 36
    __shared__ float red[256 * 33];                  // [k][i], pad 33
    __shared__ float rse[32];
    int b = blockIdx.x, p = blockIdx.y, tid = threadIdx.x;
    int k = tid & 255, jq = tid >> 8;

    if (tid < 32) rse[tid] = 1.0f / sef[(b << 5) + tid];
    __syncthreads();
    for (int idx = tid; idx < 4096; idx += 1024) {
        int i = idx >> 7, jl = idx & 127;
        c_lds[jl * 36 + i] = emat[(long)(((b << 5) + i) << 10) + (p << 7) + jl] * rse[i];
    }
    __syncthreads();

    // preload 32 u's (32 independent loads in flight per thread)
    const float* Up = U + (((b << 10) + (p << 7) + (jq << 5)) << 8) + k;
    float u[32];
    #pragma unroll
    for (int jj = 0; jj < 32; ++jj) u[jj] = Up[jj << 8];

    float acc[32];
    #pragma unroll
    for (int i = 0; i < 32; ++i) acc[i] = 0.f;

    #pragma unroll
    for (int jj = 0; jj < 32; ++jj) {
        const float4* c4 = (const float4*)(c_lds + ((jq << 5) + jj) * 36);
        float uu = u[jj];
        #pragma unroll
        for (int ii = 0; ii < 8; ++ii) {
            float4 c = c4[ii];                 // wave-uniform: LDS broadcast
            acc[ii * 4 + 0] += c.x * uu;
            acc[ii * 4 + 1] += c.y * uu;
            acc[ii * 4 + 2] += c.z * uu;
            acc[ii * 4 + 3] += c.w * uu;
        }
    }

    // cross-jq reduction in LDS (k*33+i is conflict-free across k-lanes)
    if (jq == 0) {
        #pragma unroll
        for (int i = 0; i < 32; ++i) red[k * 33 + i] = acc[i];
    }
    __syncthreads();
    for (int r = 1; r <= 2; ++r) {
        if (jq == r) {
            #pragma unroll
            for (int i = 0; i < 32; ++i) red[k * 33 + i] += acc[i];
        }
        __syncthreads();
    }
    if (jq == 3) {
        #pragma unroll
        for (int i = 0; i < 32; ++i)
            tp[(((p << 10) + (b << 5) + i) << 8) + k] = red[k * 33 + i] + acc[i];
    }
}

// ---------------------------------------------------------------------------
extern "C" void kernel_launch(void* const* d_in, const int* in_sizes, int n_in,
                              void* d_out, int out_size, void* d_ws, size_t ws_size,
                              hipStream_t stream) {
    const float* U = (const float*)d_in[0];   // [32,1024,256]
    const float* W = (const float*)d_in[1];   // [256,2048]
    float* out = (float*)d_out;               // [32,32,64]
    float* ws = (float*)d_ws;

    // ws layout (floats); total 3,606,528 = 14.43 MB
    float* tp   = ws;                  // [8][32][32][256] = 2,097,152
    float* t0p  = tp + 2097152;        // [32][16][256]    =   131,072
    float* emat = t0p + 131072;        // [32][32][1024]   = 1,048,576
    float* wbt  = emat + 1048576;      // [32][256][32]    =   262,144
    float* sef  = wbt + 262144;        // [2][1024]        =     2,048
    float* vscr = sef + 2048;          // [32][32][64]     =    65,536

    hipMemsetAsync(sef, 0, 2 * 1024 * sizeof(float), stream);

    // iter 0: uniform c -> column mean
    k_colmean<<<dim3(32, 16), 256, 0, stream>>>(U, t0p);
    k_sv<<<1024, 256, 0, stream>>>(t0p, 0, W, vscr, wbt);
    // iter 1
    k_bupd<<<dim3(32, 32), 256, 0, stream>>>(U, wbt, emat, sef, 0);
    k_ctu<<<dim3(32, 8), 1024, 0, stream>>>(U, emat, sef, tp);
    k_sv<<<1024, 256, 0, stream>>>(tp, 1, W, vscr, wbt);
    // iter 2 (final: v -> d_out)
    k_bupd<<<dim3(32, 32), 256, 0, stream>>>(U, wbt, emat, sef + 1024, 1);
    k_ctu<<<dim3(32, 8), 1024, 0, stream>>>(U, emat, sef + 1024, tp);
    k_sv<<<1024, 256, 0, stream>>>(tp, 1, W, out, wbt);
}